// Round 15
// baseline (68.321 us; speedup 1.0000x reference)
//
#include <hip/hip_runtime.h>

typedef __attribute__((ext_vector_type(2))) float f2;
typedef __attribute__((ext_vector_type(4))) float f4;
typedef __attribute__((ext_vector_type(4))) float f32x4;
typedef __attribute__((ext_vector_type(4))) unsigned u32x4;
typedef __attribute__((ext_vector_type(8))) short bf16x8;

#define NK 64
#define NC 128
#define NP 4096
#define NN 32
#define EPSV 1e-12f

#define PCH 64                     // positions per chunk
#define CPB 4                      // chunks per block
#define NGRPX (NP / (PCH * CPB))   // 16 -> grid.x

// ---- SLAB-mode ws layout (floats) ----
#define WS_WF_SL 0                               // 8192 floats (W frags)
#define WS_SS    8192                            // 16*32*64 = 32768 (S slabs)
#define WS_VP    (8192 + 32768)                  // vlad slabs: 16*32*8192
#define WS_SLAB_TOTAL (WS_VP + NGRPX * NN * NK * NC)   // 4,235,264 floats

// ---- fallback (atomic) ws layout (floats) ----
#define FB_VLAD 0
#define FB_S    (NN * NK * NC)          // 262144
#define FB_G    (FB_S + NN * NK)        // +2048
#define FB_WF   (FB_G + NN)             // +32
#define FB_TOTAL (FB_WF + 8192)

__device__ __forceinline__ unsigned short f2bf(float x) {
  unsigned u = __builtin_bit_cast(unsigned, x);
  u += 0x7fffu + ((u >> 16) & 1u);      // RTNE
  return (unsigned short)(u >> 16);
}
__device__ __forceinline__ float bf2f(unsigned short h) {
  unsigned u = ((unsigned)h) << 16;
  return __builtin_bit_cast(float, u);
}
// packed RTNE bf16 convert: low16 = bf16(a), high16 = bf16(b)
__device__ __forceinline__ unsigned cvtpk(float a, float b) {
  unsigned r;
  asm volatile("v_cvt_pk_bf16_f32 %0, %1, %2" : "=v"(r) : "v"(a), "v"(b));
  return r;
}
__device__ __forceinline__ float asf(unsigned u) { return __builtin_bit_cast(float, u); }

// raw barrier: orders LDS only (lgkmcnt), leaves global loads in flight (no vmcnt drain)
__device__ __forceinline__ void barrier_lds() {
  asm volatile("s_waitcnt lgkmcnt(0)" ::: "memory");
  __builtin_amdgcn_s_barrier();
  asm volatile("" ::: "memory");
  __builtin_amdgcn_sched_barrier(0);
}

__global__ void nv_zero(float* __restrict__ ws) {
  int i = blockIdx.x * blockDim.x + threadIdx.x;
  int stride = gridDim.x * blockDim.x;
  for (; i < FB_WF; i += stride) ws[i] = 0.0f;
}

// Precompute W fragments (hi/lo bf16) laid out per-lane for direct b128 loads.
// slot = ((kt*4 + ct)*2 + hl)*64 + lane ; elem j = conv_w[16kt+r][32ct+8g+j]
__global__ void nv_wfrag(const float* __restrict__ conv_w, unsigned short* __restrict__ wfrag) {
  int idx = blockIdx.x * 256 + threadIdx.x;   // 2048 lane-slots
  if (idx >= 2048) return;
  int lane = idx & 63, hl = (idx >> 6) & 1, ct = (idx >> 7) & 3, kt = idx >> 9;
  int r = lane & 15, g = lane >> 4;
  const float* src = conv_w + (16 * kt + r) * NC + 32 * ct + 8 * g;
  unsigned short o[8];
#pragma unroll
  for (int j = 0; j < 8; ++j) {
    float v = src[j];
    unsigned short h = f2bf(v);
    o[j] = hl ? f2bf(v - bf2f(h)) : h;
  }
  u32x4 pk;
#pragma unroll
  for (int m = 0; m < 4; ++m) pk[m] = (unsigned)o[2 * m] | ((unsigned)o[2 * m + 1] << 16);
  *reinterpret_cast<u32x4*>(wfrag + (size_t)idx * 8) = pk;
}

// Fused main: xh eliminated (vlad gathers hi from xhl_t via col-XOR map);
// 44.3 KB LDS + forced 85 VGPR -> target 3 blocks/CU (24 waves).
// Grid (16, 32), 512 threads = 8 waves.
// Wave w: logits p-tile (w&3), k-pair (w>>2); vlad k-tile (w&3), p-half (w>>2).
// Storage map: xhl_t logical (p, c) stored at col c ^ (16*((p>>3)&3)).
template <bool SLAB>
__global__ __launch_bounds__(512, 3)
void nv_main(const float* __restrict__ x, const unsigned short* __restrict__ wfrag,
             const float* __restrict__ conv_b, float* __restrict__ vout,
             float* __restrict__ sout) {
  __shared__ __align__(16) unsigned xhl_t[PCH][132];        // (hi<<16|lo), col-mapped (33792 B)
  __shared__ __align__(16) unsigned short a_lds[NK][72];    // [k][p] bf16(a*inv)      (9216 B)
  __shared__ __align__(16) float inv_lds[PCH];              //                         (256 B)
  __shared__ __align__(16) float mx_buf[2][PCH];            //                         (512 B)
  __shared__ __align__(16) float sum_buf[2][PCH];           //                         (512 B)
  // s_red aliases xhl_t floats [8192..8447] (epilogue only)     total: 44288 B

  const int tid = threadIdx.x;
  const int lane = tid & 63;
  const int w = tid >> 6;
  const int r = lane & 15;
  const int g = lane >> 4;
  const int n = blockIdx.y;
  const int p0loc = (w & 3) << 4;   // logits p-tile base
  const int kp = w >> 2;            // k-pair (softmax side)
  const int ktg0 = kp << 1;         // global kt base
  const int kw = w & 3;             // vlad k-tile
  const int ph = w >> 2;            // vlad p-half

  // ---- W hi+lo frags for own k-pair: PERSISTENT in registers (16 x b128 = 64 VGPR) ----
  bf16x8 whi_r[2][4], wlo_r[2][4];
#pragma unroll
  for (int kt2 = 0; kt2 < 2; ++kt2)
#pragma unroll
    for (int ct = 0; ct < 4; ++ct) {
      const size_t slot = (size_t)(((ktg0 + kt2) * 4 + ct) * 2);
      whi_r[kt2][ct] = *reinterpret_cast<const bf16x8*>(wfrag + (slot * 64 + lane) * 8);
      wlo_r[kt2][ct] = *reinterpret_cast<const bf16x8*>(wfrag + ((slot + 1) * 64 + lane) * 8);
    }
  float bb[2];
#pragma unroll
  for (int kt2 = 0; kt2 < 2; ++kt2) bb[kt2] = conv_b[16 * (ktg0 + kt2) + r];

  f32x4 vacc[8];
#pragma unroll
  for (int t = 0; t < 8; ++t) vacc[t] = (f32x4){0.f, 0.f, 0.f, 0.f};
  float s_part[2] = {0.f, 0.f};

  const int cst = tid & 127;           // staging channel
  const int pq = tid >> 7;             // staging p-quarter (16 p)
  const int pbase = blockIdx.x * (CPB * PCH);
  const float* xrow = x + ((size_t)n * NC + cst) * NP + 16 * pq;
  // per-lane col-map XOR for logits A-frag rows (row = p0loc + r)
  const int sxor = (((p0loc + r) >> 3) & 3) << 4;

  f4 pre[4];

  // stage xhl_t from pre (col-mapped)
  auto STAGE_XHL = [&]() {
#pragma unroll
    for (int q4 = 0; q4 < 4; ++q4) {
      f4 v = pre[q4];
      const int pl = 16 * pq + 4 * q4;
      const int ccs = cst ^ ((((pl >> 3) & 3)) << 4);   // rows pl..pl+3 share pl>>3
      unsigned h01 = cvtpk(v[0], v[1]);
      unsigned h23 = cvtpk(v[2], v[3]);
      float r0 = v[0] - asf(h01 << 16);
      float r1 = v[1] - asf(h01 & 0xffff0000u);
      float r2 = v[2] - asf(h23 << 16);
      float r3 = v[3] - asf(h23 & 0xffff0000u);
      unsigned l01 = cvtpk(r0, r1);
      unsigned l23 = cvtpk(r2, r3);
      xhl_t[pl + 0][ccs] = __builtin_amdgcn_perm(h01, l01, 0x05040100u);
      xhl_t[pl + 1][ccs] = __builtin_amdgcn_perm(h01, l01, 0x07060302u);
      xhl_t[pl + 2][ccs] = __builtin_amdgcn_perm(h23, l23, 0x05040100u);
      xhl_t[pl + 3][ccs] = __builtin_amdgcn_perm(h23, l23, 0x07060302u);
    }
  };

  // ---- prologue: load chunk 0 ----
#pragma unroll
  for (int q4 = 0; q4 < 4; ++q4)
    pre[q4] = *reinterpret_cast<const f4*>(xrow + pbase + 4 * q4);

  for (int cc = 0; cc < CPB; ++cc) {
    // ---- stage chunk cc (xhl_t free: vlad(cc-1) finished before B4) ----
    STAGE_XHL();
    barrier_lds();   // B1: staged tile visible
    // ---- prefetch next chunk (stays in flight across raw barriers) ----
    if (cc + 1 < CPB) {
      const float* xb = xrow + pbase + (cc + 1) * PCH;
#pragma unroll
      for (int q4 = 0; q4 < 4; ++q4)
        pre[q4] = *reinterpret_cast<const f4*>(xb + 4 * q4);
    }
    // ---- A-frags + norm-diag MFMA + logits MFMA (all W operands in regs) ----
    f32x4 d1 = {0.f, 0.f, 0.f, 0.f}, d2 = {0.f, 0.f, 0.f, 0.f};
    f32x4 lac[2];
    lac[0] = (f32x4){0.f, 0.f, 0.f, 0.f};
    lac[1] = (f32x4){0.f, 0.f, 0.f, 0.f};
#pragma unroll
    for (int ct = 0; ct < 4; ++ct) {
      const unsigned* row = &xhl_t[p0loc + r][(32 * ct + 8 * g) ^ sxor];
      u32x4 wA = *reinterpret_cast<const u32x4*>(row);
      u32x4 wB = *reinterpret_cast<const u32x4*>(row + 4);
      unsigned wv8[8] = {wA[0], wA[1], wA[2], wA[3], wB[0], wB[1], wB[2], wB[3]};
      u32x4 hh, ll;
#pragma unroll
      for (int m = 0; m < 4; ++m) {
        hh[m] = __builtin_amdgcn_perm(wv8[2 * m + 1], wv8[2 * m], 0x07060302u);
        ll[m] = __builtin_amdgcn_perm(wv8[2 * m + 1], wv8[2 * m], 0x05040100u);
      }
      bf16x8 Ah = __builtin_bit_cast(bf16x8, hh);
      bf16x8 Al = __builtin_bit_cast(bf16x8, ll);
      d1 = __builtin_amdgcn_mfma_f32_16x16x32_bf16(Ah, Ah, d1, 0, 0, 0);
      d2 = __builtin_amdgcn_mfma_f32_16x16x32_bf16(Ah, Al, d2, 0, 0, 0);
#pragma unroll
      for (int kt2 = 0; kt2 < 2; ++kt2) {
        lac[kt2] = __builtin_amdgcn_mfma_f32_16x16x32_bf16(Ah, whi_r[kt2][ct], lac[kt2], 0, 0, 0);
        lac[kt2] = __builtin_amdgcn_mfma_f32_16x16x32_bf16(Al, whi_r[kt2][ct], lac[kt2], 0, 0, 0);
        lac[kt2] = __builtin_amdgcn_mfma_f32_16x16x32_bf16(Ah, wlo_r[kt2][ct], lac[kt2], 0, 0, 0);
      }
    }
    // diag lanes (row 4g+i == col r) hold ||x||^2 for p = p0loc + r
    if ((r >> 2) == g) {
      int i = r & 3;
      float nsq = d1[i] + 2.0f * d2[i];
      inv_lds[p0loc + r] = __builtin_amdgcn_rsqf(fmaxf(nsq, 1e-24f));
    }
    asm volatile("s_waitcnt lgkmcnt(0)" ::: "memory");
    __builtin_amdgcn_sched_barrier(0);
    f4 ivv = *reinterpret_cast<const f4*>(&inv_lds[p0loc + 4 * g]);
    // ---- partial softmax over own 32 k ----
    float lt[2][4], e[2][4], mpart[4], sp[4];
#pragma unroll
    for (int kt2 = 0; kt2 < 2; ++kt2)
#pragma unroll
      for (int i = 0; i < 4; ++i) lt[kt2][i] = lac[kt2][i] * ivv[i] + bb[kt2];
#pragma unroll
    for (int i = 0; i < 4; ++i) mpart[i] = fmaxf(lt[0][i], lt[1][i]);
#pragma unroll
    for (int o = 1; o <= 8; o <<= 1)
#pragma unroll
      for (int i = 0; i < 4; ++i) mpart[i] = fmaxf(mpart[i], __shfl_xor(mpart[i], o));
#pragma unroll
    for (int i = 0; i < 4; ++i) sp[i] = 0.f;
#pragma unroll
    for (int kt2 = 0; kt2 < 2; ++kt2)
#pragma unroll
      for (int i = 0; i < 4; ++i) {
        e[kt2][i] = __expf(lt[kt2][i] - mpart[i]);
        sp[i] += e[kt2][i];
      }
#pragma unroll
    for (int o = 1; o <= 8; o <<= 1)
#pragma unroll
      for (int i = 0; i < 4; ++i) sp[i] += __shfl_xor(sp[i], o);
    if (r < 4) mx_buf[kp][p0loc + 4 * g + r] = mpart[r];
    else if (r < 8) sum_buf[kp][p0loc + 4 * g + (r - 4)] = sp[r - 4];
    barrier_lds();   // B2: partial (m,s) exchanged
    // ---- combine both k-pairs (online softmax), write a_lds ----
    {
      f4 m0 = *reinterpret_cast<const f4*>(&mx_buf[0][p0loc + 4 * g]);
      f4 m1 = *reinterpret_cast<const f4*>(&mx_buf[1][p0loc + 4 * g]);
      f4 s0 = *reinterpret_cast<const f4*>(&sum_buf[0][p0loc + 4 * g]);
      f4 s1 = *reinterpret_cast<const f4*>(&sum_buf[1][p0loc + 4 * g]);
      float fcorr[4];
#pragma unroll
      for (int i = 0; i < 4; ++i) {
        float m = fmaxf(m0[i], m1[i]);
        float c0 = __expf(m0[i] - m);
        float c1 = __expf(m1[i] - m);
        float tot = s0[i] * c0 + s1[i] * c1;
        fcorr[i] = (kp == 0 ? c0 : c1) * __builtin_amdgcn_rcpf(tot);
      }
#pragma unroll
      for (int kt2 = 0; kt2 < 2; ++kt2) {
        float av[4];
#pragma unroll
        for (int i = 0; i < 4; ++i) {
          float a = e[kt2][i] * fcorr[i];
          s_part[kt2] += a;
          av[i] = a * ivv[i];
        }
        unsigned* arow = reinterpret_cast<unsigned*>(&a_lds[16 * (ktg0 + kt2) + r][p0loc + 4 * g]);
        arow[0] = cvtpk(av[0], av[1]);
        arow[1] = cvtpk(av[2], av[3]);
      }
    }
    barrier_lds();   // B3: a_lds visible
    // ---- vlad: k-tile kw x 128c over own 32-p half; B-frags gathered from xhl_t ----
    {
      bf16x8 af = *reinterpret_cast<const bf16x8*>(&a_lds[16 * kw + r][32 * ph + 8 * g]);
      const int prow0 = 8 * (4 * ph + g);          // (prow0>>3)&3 == g
#pragma unroll
      for (int tcl = 0; tcl < 8; ++tcl) {
        const int ccol = ((tcl << 4) + r) ^ (g << 4);   // stored col for these rows
        unsigned u[8];
#pragma unroll
        for (int j = 0; j < 8; ++j) u[j] = xhl_t[prow0 + j][ccol];
        u32x4 hb;
#pragma unroll
        for (int m = 0; m < 4; ++m)
          hb[m] = __builtin_amdgcn_perm(u[2 * m + 1], u[2 * m], 0x07060302u);
        vacc[tcl] = __builtin_amdgcn_mfma_f32_16x16x32_bf16(af, __builtin_bit_cast(bf16x8, hb),
                                                            vacc[tcl], 0, 0, 0);
      }
    }
    barrier_lds();   // B4: vlad reads done; xhl_t free for next stage / epilogue
  }

  // ---- epilogue: pair-combine vlad partials in LDS (reuse xhl_t) ----
  float* cbuf = reinterpret_cast<float*>(&xhl_t[0][0]);   // floats [0..8191]
  float* s_red = cbuf + 8192;                              // floats [8192..8447]
  if (w < 4) {
#pragma unroll
    for (int tcl = 0; tcl < 8; ++tcl)
#pragma unroll
      for (int i = 0; i < 4; ++i)
        cbuf[kw * 2048 + (4 * g + i) * 128 + (tcl << 4) + r] = vacc[tcl][i];
  }
  // S: reduce over g groups within wave, park in s_red
#pragma unroll
  for (int kt2 = 0; kt2 < 2; ++kt2) {
    float v = s_part[kt2];
    v += __shfl_xor(v, 16);
    v += __shfl_xor(v, 32);
    if (g == 0) s_red[(kp * 4 + (w & 3)) * 32 + kt2 * 16 + r] = v;
  }
  barrier_lds();   // B5
  if (w >= 4) {
#pragma unroll
    for (int tcl = 0; tcl < 8; ++tcl)
#pragma unroll
      for (int i = 0; i < 4; ++i) {
        const int idx = kw * 2048 + (4 * g + i) * 128 + (tcl << 4) + r;
        float v = vacc[tcl][i] + cbuf[idx];
        if constexpr (SLAB) cbuf[idx] = v;
        else atomicAdd(&vout[((size_t)n * NK + 16 * kw + 4 * g + i) * NC + (tcl << 4) + r], v);
      }
  }
  if (tid < 64) {
    float S = 0.f;
#pragma unroll
    for (int pt = 0; pt < 4; ++pt) S += s_red[((tid >> 5) * 4 + pt) * 32 + (tid & 31)];
    if constexpr (SLAB) sout[((size_t)blockIdx.x * NN + n) * NK + tid] = S;
    else atomicAdd(&sout[n * NK + tid], S);
  }
  if constexpr (SLAB) {
    barrier_lds();   // B6: combined tile in cbuf
    float* dst = vout + ((size_t)blockIdx.x * NN + n) * (NK * NC);
#pragma unroll
    for (int m = 0; m < 4; ++m) {
      const int idx = m * 512 + tid;
      *reinterpret_cast<f4*>(dst + 4 * idx) = *reinterpret_cast<const f4*>(cbuf + 4 * idx);
    }
  }
}

// SLAB finalize: 1 wave per (n,k), float2 lanes. Grid (NK/4, NN) x 256 thr.
__global__ __launch_bounds__(256)
void nv_finalize2(const float* __restrict__ vin, const float* __restrict__ sin,
                  const float* __restrict__ centroids, float* __restrict__ out) {
  const int wv = threadIdx.x >> 6;
  const int lane = threadIdx.x & 63;
  const int k = blockIdx.x * 4 + wv;
  const int n = blockIdx.y;
  const int c0 = lane * 2;
  f2 v = {0.f, 0.f};
#pragma unroll
  for (int sx = 0; sx < NGRPX; ++sx) {
    const float* vr = vin + ((size_t)sx * NN + n) * (NK * NC) + k * NC;
    f2 t = *reinterpret_cast<const f2*>(vr + c0);
    v.x += t.x;
    v.y += t.y;
  }
  float sv = (lane < 16) ? sin[((size_t)lane * NN + n) * NK + k] : 0.f;
#pragma unroll
  for (int o = 1; o <= 8; o <<= 1) sv += __shfl_xor(sv, o);
  float S = __shfl(sv, 0);
  f2 ce = *reinterpret_cast<const f2*>(centroids + k * NC + c0);
  v.x -= S * ce.x;
  v.y -= S * ce.y;
  float ss = v.x * v.x + v.y * v.y;
#pragma unroll
  for (int o = 1; o < 64; o <<= 1) ss += __shfl_xor(ss, o);
  float inv = 0.125f / fmaxf(sqrtf(ss), EPSV);  // global norm is exactly 8
  f2 ov = {v.x * inv, v.y * inv};
  *reinterpret_cast<f2*>(out + ((size_t)n * NK + k) * NC + c0) = ov;
}

// Fallback finalize (atomic mode)
__global__ void nv_finalize(const float* __restrict__ vin, const float* __restrict__ sin,
                            const float* __restrict__ centroids,
                            float* __restrict__ out, float* __restrict__ gnorm) {
  const int k = blockIdx.x;
  const int n = blockIdx.y;
  const int t = threadIdx.x;  // 64 threads
  float S = sin[n * NK + k];
  const size_t base = ((size_t)n * NK + k) * NC;
  float v0 = vin[base + t] - S * centroids[k * NC + t];
  float v1 = vin[base + t + 64] - S * centroids[k * NC + t + 64];
  float ss = v0 * v0 + v1 * v1;
#pragma unroll
  for (int off = 1; off < 64; off <<= 1) ss += __shfl_xor(ss, off);
  float inv = 1.0f / fmaxf(sqrtf(ss), EPSV);
  out[base + t] = v0 * inv;
  out[base + t + 64] = v1 * inv;
  if (t == 0) atomicAdd(&gnorm[n], ss * inv * inv);
}

__global__ void nv_scale(float* __restrict__ out, const float* __restrict__ gnorm) {
  int i = blockIdx.x * blockDim.x + threadIdx.x;  // 262144 elements
  int n = i >> 13;
  out[i] *= 1.0f / fmaxf(sqrtf(gnorm[n]), EPSV);
}

extern "C" void kernel_launch(void* const* d_in, const int* in_sizes, int n_in,
                              void* d_out, int out_size, void* d_ws, size_t ws_size,
                              hipStream_t stream) {
  const float* x = (const float*)d_in[0];
  const float* conv_w = (const float*)d_in[1];
  const float* conv_b = (const float*)d_in[2];
  const float* centroids = (const float*)d_in[3];
  float* out = (float*)d_out;
  float* ws = (float*)d_ws;

  if (ws_size >= (size_t)WS_SLAB_TOTAL * sizeof(float)) {
    unsigned short* wfrag = (unsigned short*)(ws + WS_WF_SL);
    float* sp = ws + WS_SS;
    float* vp = ws + WS_VP;
    nv_wfrag<<<8, 256, 0, stream>>>(conv_w, wfrag);
    nv_main<true><<<dim3(NGRPX, NN), 512, 0, stream>>>(x, wfrag, conv_b, vp, sp);
    nv_finalize2<<<dim3(NK / 4, NN), 256, 0, stream>>>(vp, sp, centroids, out);
  } else {
    float* vlad_acc = ws + FB_VLAD;
    float* s_acc = ws + FB_S;
    float* gnorm = ws + FB_G;
    unsigned short* wfrag = (unsigned short*)(ws + FB_WF);
    nv_zero<<<256, 256, 0, stream>>>(ws);
    nv_wfrag<<<8, 256, 0, stream>>>(conv_w, wfrag);
    nv_main<false><<<dim3(NGRPX, NN), 512, 0, stream>>>(x, wfrag, conv_b, vlad_acc, s_acc);
    nv_finalize<<<dim3(NK, NN), 64, 0, stream>>>(vlad_acc, s_acc, centroids, out, gnorm);
    nv_scale<<<1024, 256, 0, stream>>>(out, gnorm);
  }
}

// Round 16
// 44.685 us; speedup vs baseline: 1.5290x; 1.5290x over previous
//
#include <hip/hip_runtime.h>

typedef __attribute__((ext_vector_type(2))) float f2;
typedef __attribute__((ext_vector_type(4))) float f4;
typedef __attribute__((ext_vector_type(4))) float f32x4;
typedef __attribute__((ext_vector_type(4))) unsigned u32x4;
typedef __attribute__((ext_vector_type(8))) short bf16x8;

#define NK 64
#define NC 128
#define NP 4096
#define NN 32
#define EPSV 1e-12f

#define PCH 64                     // positions per chunk
#define CPB 4                      // chunks per block
#define NGRPX (NP / (PCH * CPB))   // 16 -> grid.x

// ---- SLAB-mode ws layout (floats) ----
#define WS_WF_SL 0                               // 8192 floats (W frags)
#define WS_SS    8192                            // 16*32*64 = 32768 (S slabs)
#define WS_VP    (8192 + 32768)                  // vlad slabs: 16*32*8192
#define WS_SLAB_TOTAL (WS_VP + NGRPX * NN * NK * NC)   // 4,235,264 floats

// ---- fallback (atomic) ws layout (floats) ----
#define FB_VLAD 0
#define FB_S    (NN * NK * NC)          // 262144
#define FB_G    (FB_S + NN * NK)        // +2048
#define FB_WF   (FB_G + NN)             // +32
#define FB_TOTAL (FB_WF + 8192)

__device__ __forceinline__ unsigned short f2bf(float x) {
  unsigned u = __builtin_bit_cast(unsigned, x);
  u += 0x7fffu + ((u >> 16) & 1u);      // RTNE
  return (unsigned short)(u >> 16);
}
__device__ __forceinline__ float bf2f(unsigned short h) {
  unsigned u = ((unsigned)h) << 16;
  return __builtin_bit_cast(float, u);
}
// packed RTNE bf16 convert: low16 = bf16(a), high16 = bf16(b)
__device__ __forceinline__ unsigned cvtpk(float a, float b) {
  unsigned r;
  asm volatile("v_cvt_pk_bf16_f32 %0, %1, %2" : "=v"(r) : "v"(a), "v"(b));
  return r;
}
__device__ __forceinline__ float asf(unsigned u) { return __builtin_bit_cast(float, u); }

// raw barrier: orders LDS only (lgkmcnt), leaves global loads in flight (no vmcnt drain)
__device__ __forceinline__ void barrier_lds() {
  asm volatile("s_waitcnt lgkmcnt(0)" ::: "memory");
  __builtin_amdgcn_s_barrier();
  asm volatile("" ::: "memory");
  __builtin_amdgcn_sched_barrier(0);
}

__global__ void nv_zero(float* __restrict__ ws) {
  int i = blockIdx.x * blockDim.x + threadIdx.x;
  int stride = gridDim.x * blockDim.x;
  for (; i < FB_WF; i += stride) ws[i] = 0.0f;
}

// Precompute W fragments (hi/lo bf16) laid out per-lane for direct b128 loads.
// slot = ((kt*4 + ct)*2 + hl)*64 + lane ; elem j = conv_w[16kt+r][32ct+8g+j]
__global__ void nv_wfrag(const float* __restrict__ conv_w, unsigned short* __restrict__ wfrag) {
  int idx = blockIdx.x * 256 + threadIdx.x;   // 2048 lane-slots
  if (idx >= 2048) return;
  int lane = idx & 63, hl = (idx >> 6) & 1, ct = (idx >> 7) & 3, kt = idx >> 9;
  int r = lane & 15, g = lane >> 4;
  const float* src = conv_w + (16 * kt + r) * NC + 32 * ct + 8 * g;
  unsigned short o[8];
#pragma unroll
  for (int j = 0; j < 8; ++j) {
    float v = src[j];
    unsigned short h = f2bf(v);
    o[j] = hl ? f2bf(v - bf2f(h)) : h;
  }
  u32x4 pk;
#pragma unroll
  for (int m = 0; m < 4; ++m) pk[m] = (unsigned)o[2 * m] | ((unsigned)o[2 * m + 1] << 16);
  *reinterpret_cast<u32x4*>(wfrag + (size_t)idx * 8) = pk;
}

// Fused main (3-barrier/chunk; ALL W fragments in registers: 16 x b128 = 64 VGPR).
// Grid (16, 32), 512 threads = 8 waves, 2 blocks/CU.
// Wave w: logits p-tile (w&3), k-pair (w>>2); vlad k-tile (w&3), p-half (w>>2).
template <bool SLAB>
__global__ __launch_bounds__(512, 2)
void nv_main(const float* __restrict__ x, const unsigned short* __restrict__ wfrag,
             const float* __restrict__ conv_b, float* __restrict__ vout,
             float* __restrict__ sout) {
  __shared__ __align__(16) unsigned xhl_t[PCH][132];        // [p][c] u32 = hi<<16|lo (33792 B)
  __shared__ __align__(16) unsigned short xh[NC][72];       // [c][p^swz] hi          (18432 B)
  __shared__ __align__(16) unsigned short a_lds[NK][72];    // [k][p] bf16(a*inv)     (9216 B)
  __shared__ __align__(16) float inv_lds[PCH];              //                        (256 B)
  __shared__ __align__(16) float mx_buf[2][PCH];            //                        (512 B)
  __shared__ __align__(16) float sum_buf[2][PCH];           //                        (512 B)
  // s_red aliases xhl_t floats [8192..8447] (epilogue only)    total: 62720 B

  const int tid = threadIdx.x;
  const int lane = tid & 63;
  const int w = tid >> 6;
  const int r = lane & 15;
  const int g = lane >> 4;
  const int n = blockIdx.y;
  const int p0loc = (w & 3) << 4;   // logits p-tile base
  const int kp = w >> 2;            // k-pair (softmax side)
  const int ktg0 = kp << 1;         // global kt base
  const int kw = w & 3;             // vlad k-tile
  const int ph = w >> 2;            // vlad p-half

  // ---- W hi+lo frags for own k-pair: PERSISTENT in registers (16 x b128 = 64 VGPR) ----
  bf16x8 whi_r[2][4], wlo_r[2][4];
#pragma unroll
  for (int kt2 = 0; kt2 < 2; ++kt2)
#pragma unroll
    for (int ct = 0; ct < 4; ++ct) {
      const size_t slot = (size_t)(((ktg0 + kt2) * 4 + ct) * 2);
      whi_r[kt2][ct] = *reinterpret_cast<const bf16x8*>(wfrag + (slot * 64 + lane) * 8);
      wlo_r[kt2][ct] = *reinterpret_cast<const bf16x8*>(wfrag + ((slot + 1) * 64 + lane) * 8);
    }
  float bb[2];
#pragma unroll
  for (int kt2 = 0; kt2 < 2; ++kt2) bb[kt2] = conv_b[16 * (ktg0 + kt2) + r];

  f32x4 vacc[8];
#pragma unroll
  for (int t = 0; t < 8; ++t) vacc[t] = (f32x4){0.f, 0.f, 0.f, 0.f};
  float s_part[2] = {0.f, 0.f};

  const int cst = tid & 127;           // staging channel
  const int pq = tid >> 7;             // staging p-quarter (16 p)
  const int swst = ((cst >> 3) & 3) << 3;
  const int pbase = blockIdx.x * (CPB * PCH);
  const float* xrow = x + ((size_t)n * NC + cst) * NP + 16 * pq;

  f4 pre[4];
  unsigned hs[8];   // saved hi-words (for deferred xh writes)

  // stage xhl_t from pre; save hi-words in hs
  auto STAGE_XHL = [&]() {
#pragma unroll
    for (int q4 = 0; q4 < 4; ++q4) {
      f4 v = pre[q4];
      const int pl = 16 * pq + 4 * q4;
      unsigned h01 = cvtpk(v[0], v[1]);
      unsigned h23 = cvtpk(v[2], v[3]);
      float r0 = v[0] - asf(h01 << 16);
      float r1 = v[1] - asf(h01 & 0xffff0000u);
      float r2 = v[2] - asf(h23 << 16);
      float r3 = v[3] - asf(h23 & 0xffff0000u);
      unsigned l01 = cvtpk(r0, r1);
      unsigned l23 = cvtpk(r2, r3);
      hs[2 * q4] = h01;
      hs[2 * q4 + 1] = h23;
      xhl_t[pl + 0][cst] = __builtin_amdgcn_perm(h01, l01, 0x05040100u);
      xhl_t[pl + 1][cst] = __builtin_amdgcn_perm(h01, l01, 0x07060302u);
      xhl_t[pl + 2][cst] = __builtin_amdgcn_perm(h23, l23, 0x05040100u);
      xhl_t[pl + 3][cst] = __builtin_amdgcn_perm(h23, l23, 0x07060302u);
    }
  };
  // deferred: write swizzled xh rows from saved hi-words
  auto WRITE_XH = [&]() {
#pragma unroll
    for (int q4 = 0; q4 < 4; ++q4) {
      const int pp = (16 * pq + 4 * q4) ^ swst;
      *reinterpret_cast<unsigned*>(&xh[cst][pp]) = hs[2 * q4];
      *reinterpret_cast<unsigned*>(&xh[cst][pp + 2]) = hs[2 * q4 + 1];
    }
  };

  // ---- prologue: load chunk 0, stage xhl_t(0) ----
#pragma unroll
  for (int q4 = 0; q4 < 4; ++q4)
    pre[q4] = *reinterpret_cast<const f4*>(xrow + pbase + 4 * q4);
  STAGE_XHL();
  barrier_lds();   // B1(0): xhl_t(0) visible

  for (int cc = 0; cc < CPB; ++cc) {
    // ---- deferred xh(cc) writes (visible by B2; vlad reads after B3) ----
    WRITE_XH();
    // ---- prefetch next chunk (stays in flight across raw barriers) ----
    if (cc + 1 < CPB) {
      const float* xb = xrow + pbase + (cc + 1) * PCH;
#pragma unroll
      for (int q4 = 0; q4 < 4; ++q4)
        pre[q4] = *reinterpret_cast<const f4*>(xb + 4 * q4);
    }
    // ---- A-frags + norm-diag MFMA + logits MFMA (all W operands in regs) ----
    f32x4 d1 = {0.f, 0.f, 0.f, 0.f}, d2 = {0.f, 0.f, 0.f, 0.f};
    f32x4 lac[2];
    lac[0] = (f32x4){0.f, 0.f, 0.f, 0.f};
    lac[1] = (f32x4){0.f, 0.f, 0.f, 0.f};
#pragma unroll
    for (int ct = 0; ct < 4; ++ct) {
      const unsigned* row = &xhl_t[p0loc + r][32 * ct + 8 * g];
      u32x4 wA = *reinterpret_cast<const u32x4*>(row);
      u32x4 wB = *reinterpret_cast<const u32x4*>(row + 4);
      unsigned wv8[8] = {wA[0], wA[1], wA[2], wA[3], wB[0], wB[1], wB[2], wB[3]};
      u32x4 hh, ll;
#pragma unroll
      for (int m = 0; m < 4; ++m) {
        hh[m] = __builtin_amdgcn_perm(wv8[2 * m + 1], wv8[2 * m], 0x07060302u);
        ll[m] = __builtin_amdgcn_perm(wv8[2 * m + 1], wv8[2 * m], 0x05040100u);
      }
      bf16x8 Ah = __builtin_bit_cast(bf16x8, hh);
      bf16x8 Al = __builtin_bit_cast(bf16x8, ll);
      d1 = __builtin_amdgcn_mfma_f32_16x16x32_bf16(Ah, Ah, d1, 0, 0, 0);
      d2 = __builtin_amdgcn_mfma_f32_16x16x32_bf16(Ah, Al, d2, 0, 0, 0);
#pragma unroll
      for (int kt2 = 0; kt2 < 2; ++kt2) {
        lac[kt2] = __builtin_amdgcn_mfma_f32_16x16x32_bf16(Ah, whi_r[kt2][ct], lac[kt2], 0, 0, 0);
        lac[kt2] = __builtin_amdgcn_mfma_f32_16x16x32_bf16(Al, whi_r[kt2][ct], lac[kt2], 0, 0, 0);
        lac[kt2] = __builtin_amdgcn_mfma_f32_16x16x32_bf16(Ah, wlo_r[kt2][ct], lac[kt2], 0, 0, 0);
      }
    }
    // diag lanes (row 4g+i == col r) hold ||x||^2 for p = p0loc + r
    if ((r >> 2) == g) {
      int i = r & 3;
      float nsq = d1[i] + 2.0f * d2[i];
      inv_lds[p0loc + r] = __builtin_amdgcn_rsqf(fmaxf(nsq, 1e-24f));
    }
    asm volatile("s_waitcnt lgkmcnt(0)" ::: "memory");
    __builtin_amdgcn_sched_barrier(0);
    f4 ivv = *reinterpret_cast<const f4*>(&inv_lds[p0loc + 4 * g]);
    // ---- partial softmax over own 32 k ----
    float lt[2][4], e[2][4], mpart[4], sp[4];
#pragma unroll
    for (int kt2 = 0; kt2 < 2; ++kt2)
#pragma unroll
      for (int i = 0; i < 4; ++i) lt[kt2][i] = lac[kt2][i] * ivv[i] + bb[kt2];
#pragma unroll
    for (int i = 0; i < 4; ++i) mpart[i] = fmaxf(lt[0][i], lt[1][i]);
#pragma unroll
    for (int o = 1; o <= 8; o <<= 1)
#pragma unroll
      for (int i = 0; i < 4; ++i) mpart[i] = fmaxf(mpart[i], __shfl_xor(mpart[i], o));
#pragma unroll
    for (int i = 0; i < 4; ++i) sp[i] = 0.f;
#pragma unroll
    for (int kt2 = 0; kt2 < 2; ++kt2)
#pragma unroll
      for (int i = 0; i < 4; ++i) {
        e[kt2][i] = __expf(lt[kt2][i] - mpart[i]);
        sp[i] += e[kt2][i];
      }
#pragma unroll
    for (int o = 1; o <= 8; o <<= 1)
#pragma unroll
      for (int i = 0; i < 4; ++i) sp[i] += __shfl_xor(sp[i], o);
    if (r < 4) mx_buf[kp][p0loc + 4 * g + r] = mpart[r];
    else if (r < 8) sum_buf[kp][p0loc + 4 * g + (r - 4)] = sp[r - 4];
    barrier_lds();   // B2: partial (m,s) + xh(cc) ordered
    // ---- combine both k-pairs (online softmax), write a_lds ----
    {
      f4 m0 = *reinterpret_cast<const f4*>(&mx_buf[0][p0loc + 4 * g]);
      f4 m1 = *reinterpret_cast<const f4*>(&mx_buf[1][p0loc + 4 * g]);
      f4 s0 = *reinterpret_cast<const f4*>(&sum_buf[0][p0loc + 4 * g]);
      f4 s1 = *reinterpret_cast<const f4*>(&sum_buf[1][p0loc + 4 * g]);
      float fcorr[4];
#pragma unroll
      for (int i = 0; i < 4; ++i) {
        float m = fmaxf(m0[i], m1[i]);
        float c0 = __expf(m0[i] - m);
        float c1 = __expf(m1[i] - m);
        float tot = s0[i] * c0 + s1[i] * c1;
        fcorr[i] = (kp == 0 ? c0 : c1) * __builtin_amdgcn_rcpf(tot);
      }
#pragma unroll
      for (int kt2 = 0; kt2 < 2; ++kt2) {
        float av[4];
#pragma unroll
        for (int i = 0; i < 4; ++i) {
          float a = e[kt2][i] * fcorr[i];
          s_part[kt2] += a;
          av[i] = a * ivv[i];
        }
        unsigned* arow = reinterpret_cast<unsigned*>(&a_lds[16 * (ktg0 + kt2) + r][p0loc + 4 * g]);
        arow[0] = cvtpk(av[0], av[1]);
        arow[1] = cvtpk(av[2], av[3]);
      }
    }
    barrier_lds();   // B3: a_lds (and xh) visible
    // ---- vlad (reads a_lds + xh only) CONCURRENT with xhl_t staging of next chunk ----
    {
      bf16x8 af = *reinterpret_cast<const bf16x8*>(&a_lds[16 * kw + r][32 * ph + 8 * g]);
#pragma unroll
      for (int tcl = 0; tcl < 8; ++tcl) {
        const int c = (tcl << 4) + r;
        const int pblk = ((ph << 2) + g) ^ ((c >> 3) & 3);
        bf16x8 bx = *reinterpret_cast<const bf16x8*>(&xh[c][pblk << 3]);
        vacc[tcl] = __builtin_amdgcn_mfma_f32_16x16x32_bf16(af, bx, vacc[tcl], 0, 0, 0);
      }
    }
    if (cc + 1 < CPB) STAGE_XHL();   // xhl_t(cc+1): only logits(cc) read it, done pre-B2
    barrier_lds();   // B1(cc+1): staged tile visible / epilogue guard on last iter
  }

  // ---- epilogue: pair-combine vlad partials in LDS (reuse xhl_t) ----
  float* cbuf = reinterpret_cast<float*>(&xhl_t[0][0]);   // floats [0..8191]
  float* s_red = cbuf + 8192;                              // floats [8192..8447]
  if (w < 4) {
#pragma unroll
    for (int tcl = 0; tcl < 8; ++tcl)
#pragma unroll
      for (int i = 0; i < 4; ++i)
        cbuf[kw * 2048 + (4 * g + i) * 128 + (tcl << 4) + r] = vacc[tcl][i];
  }
  // S: reduce over g groups within wave, park in s_red
#pragma unroll
  for (int kt2 = 0; kt2 < 2; ++kt2) {
    float v = s_part[kt2];
    v += __shfl_xor(v, 16);
    v += __shfl_xor(v, 32);
    if (g == 0) s_red[(kp * 4 + (w & 3)) * 32 + kt2 * 16 + r] = v;
  }
  barrier_lds();   // B5
  if (w >= 4) {
#pragma unroll
    for (int tcl = 0; tcl < 8; ++tcl)
#pragma unroll
      for (int i = 0; i < 4; ++i) {
        const int idx = kw * 2048 + (4 * g + i) * 128 + (tcl << 4) + r;
        float v = vacc[tcl][i] + cbuf[idx];
        if constexpr (SLAB) cbuf[idx] = v;
        else atomicAdd(&vout[((size_t)n * NK + 16 * kw + 4 * g + i) * NC + (tcl << 4) + r], v);
      }
  }
  if (tid < 64) {
    float S = 0.f;
#pragma unroll
    for (int pt = 0; pt < 4; ++pt) S += s_red[((tid >> 5) * 4 + pt) * 32 + (tid & 31)];
    if constexpr (SLAB) sout[((size_t)blockIdx.x * NN + n) * NK + tid] = S;
    else atomicAdd(&sout[n * NK + tid], S);
  }
  if constexpr (SLAB) {
    barrier_lds();   // B6: combined tile in cbuf
    float* dst = vout + ((size_t)blockIdx.x * NN + n) * (NK * NC);
#pragma unroll
    for (int m = 0; m < 4; ++m) {
      const int idx = m * 512 + tid;
      *reinterpret_cast<f4*>(dst + 4 * idx) = *reinterpret_cast<const f4*>(cbuf + 4 * idx);
    }
  }
}

// SLAB finalize: 1 wave per (n,k), float2 lanes. Grid (NK/4, NN) x 256 thr.
__global__ __launch_bounds__(256)
void nv_finalize2(const float* __restrict__ vin, const float* __restrict__ sin,
                  const float* __restrict__ centroids, float* __restrict__ out) {
  const int wv = threadIdx.x >> 6;
  const int lane = threadIdx.x & 63;
  const int k = blockIdx.x * 4 + wv;
  const int n = blockIdx.y;
  const int c0 = lane * 2;
  f2 v = {0.f, 0.f};
#pragma unroll
  for (int sx = 0; sx < NGRPX; ++sx) {
    const float* vr = vin + ((size_t)sx * NN + n) * (NK * NC) + k * NC;
    f2 t = *reinterpret_cast<const f2*>(vr + c0);
    v.x += t.x;
    v.y += t.y;
  }
  float sv = (lane < 16) ? sin[((size_t)lane * NN + n) * NK + k] : 0.f;
#pragma unroll
  for (int o = 1; o <= 8; o <<= 1) sv += __shfl_xor(sv, o);
  float S = __shfl(sv, 0);
  f2 ce = *reinterpret_cast<const f2*>(centroids + k * NC + c0);
  v.x -= S * ce.x;
  v.y -= S * ce.y;
  float ss = v.x * v.x + v.y * v.y;
#pragma unroll
  for (int o = 1; o < 64; o <<= 1) ss += __shfl_xor(ss, o);
  float inv = 0.125f / fmaxf(sqrtf(ss), EPSV);  // global norm is exactly 8
  f2 ov = {v.x * inv, v.y * inv};
  *reinterpret_cast<f2*>(out + ((size_t)n * NK + k) * NC + c0) = ov;
}

// Fallback finalize (atomic mode)
__global__ void nv_finalize(const float* __restrict__ vin, const float* __restrict__ sin,
                            const float* __restrict__ centroids,
                            float* __restrict__ out, float* __restrict__ gnorm) {
  const int k = blockIdx.x;
  const int n = blockIdx.y;
  const int t = threadIdx.x;  // 64 threads
  float S = sin[n * NK + k];
  const size_t base = ((size_t)n * NK + k) * NC;
  float v0 = vin[base + t] - S * centroids[k * NC + t];
  float v1 = vin[base + t + 64] - S * centroids[k * NC + t + 64];
  float ss = v0 * v0 + v1 * v1;
#pragma unroll
  for (int off = 1; off < 64; off <<= 1) ss += __shfl_xor(ss, off);
  float inv = 1.0f / fmaxf(sqrtf(ss), EPSV);
  out[base + t] = v0 * inv;
  out[base + t + 64] = v1 * inv;
  if (t == 0) atomicAdd(&gnorm[n], ss * inv * inv);
}

__global__ void nv_scale(float* __restrict__ out, const float* __restrict__ gnorm) {
  int i = blockIdx.x * blockDim.x + threadIdx.x;  // 262144 elements
  int n = i >> 13;
  out[i] *= 1.0f / fmaxf(sqrtf(gnorm[n]), EPSV);
}

extern "C" void kernel_launch(void* const* d_in, const int* in_sizes, int n_in,
                              void* d_out, int out_size, void* d_ws, size_t ws_size,
                              hipStream_t stream) {
  const float* x = (const float*)d_in[0];
  const float* conv_w = (const float*)d_in[1];
  const float* conv_b = (const float*)d_in[2];
  const float* centroids = (const float*)d_in[3];
  float* out = (float*)d_out;
  float* ws = (float*)d_ws;

  if (ws_size >= (size_t)WS_SLAB_TOTAL * sizeof(float)) {
    unsigned short* wfrag = (unsigned short*)(ws + WS_WF_SL);
    float* sp = ws + WS_SS;
    float* vp = ws + WS_VP;
    nv_wfrag<<<8, 256, 0, stream>>>(conv_w, wfrag);
    nv_main<true><<<dim3(NGRPX, NN), 512, 0, stream>>>(x, wfrag, conv_b, vp, sp);
    nv_finalize2<<<dim3(NK / 4, NN), 256, 0, stream>>>(vp, sp, centroids, out);
  } else {
    float* vlad_acc = ws + FB_VLAD;
    float* s_acc = ws + FB_S;
    float* gnorm = ws + FB_G;
    unsigned short* wfrag = (unsigned short*)(ws + FB_WF);
    nv_zero<<<256, 256, 0, stream>>>(ws);
    nv_wfrag<<<8, 256, 0, stream>>>(conv_w, wfrag);
    nv_main<false><<<dim3(NGRPX, NN), 512, 0, stream>>>(x, wfrag, conv_b, vlad_acc, s_acc);
    nv_finalize<<<dim3(NK, NN), 64, 0, stream>>>(vlad_acc, s_acc, centroids, out, gnorm);
    nv_scale<<<1024, 256, 0, stream>>>(out, gnorm);
  }
}